// Round 2
// baseline (136.387 us; speedup 1.0000x reference)
//
#include <hip/hip_runtime.h>
#include <hip/hip_bf16.h>
#include <hip/hip_fp16.h>

// NT-Xent: B=4096, D=128, N=8192, TEMP=0.5, label(i) = i ^ 4096
#define NB   4096
#define NTOT 8192
#define DD   128

typedef __attribute__((ext_vector_type(8))) _Float16 f16x8;
typedef __attribute__((ext_vector_type(4))) float    f32x4;

#if defined(__has_builtin)
#if __has_builtin(__builtin_amdgcn_exp2f)
#define EXP2F(x) __builtin_amdgcn_exp2f(x)
#else
#define EXP2F(x) exp2f(x)
#endif
#if __has_builtin(__builtin_amdgcn_logf)
#define LOG2F(x) __builtin_amdgcn_logf(x)
#else
#define LOG2F(x) log2f(x)
#endif
#else
#define EXP2F(x) exp2f(x)
#define LOG2F(x) log2f(x)
#endif

// Pre-scale normalized rows by sqrt(2*log2e) so MFMA emits acc = 2*log2e*dot.
// Then e = exp2(acc) directly (no fma), and lse - s_label = ln2*(log2(sum) - acc_label)
// since 2 + ln2*(-2*log2e) == 0 exactly.
#define SQSCALE 1.69864394f   // sqrt(2.8853900817779268)
#define LN2     0.69314718056f

// ---------------- kernel 1: row-normalize+scale fp32 -> f16; zero rowsum/out --
__global__ void knorm(const float* __restrict__ zi, const float* __restrict__ zj,
                      _Float16* __restrict__ zs, float* __restrict__ rowsum,
                      float* __restrict__ out) {
  int wave = threadIdx.x >> 6, lane = threadIdx.x & 63;
  int row = (blockIdx.x << 2) + wave;            // 2048 blocks * 4 rows
  const float* src = (row < NB) ? (zi + (size_t)row * DD)
                                : (zj + (size_t)(row - NB) * DD);
  float2 v = ((const float2*)src)[lane];         // 2 floats per lane
  float ss = v.x * v.x + v.y * v.y;
#pragma unroll
  for (int m = 1; m < 64; m <<= 1) ss += __shfl_xor(ss, m, 64);
  float inv = SQSCALE / fmaxf(sqrtf(ss), 1e-8f);
  struct H2 { _Float16 x, y; } hv;
  hv.x = (_Float16)(v.x * inv);
  hv.y = (_Float16)(v.y * inv);
  ((unsigned int*)(zs + (size_t)row * DD))[lane] = __builtin_bit_cast(unsigned int, hv);
  if (lane == 0) rowsum[row] = 0.f;
  if (blockIdx.x == 0 && threadIdx.x == 0) out[0] = 0.f;
}

// ---------------- kernel 2: sim GEMM + streaming exp-sum ----------------
// grid = 64 rowblocks * 32 col chunks = 2048 blocks, 256 thr (4 waves).
// Block: rows rb*128..+127 (wave w: +32w..+32w+31 as two 16-row strips),
//        cols chunk*256..+255 (16 tiles of 16). Register-double-buffered B.
__global__ __launch_bounds__(256) void kmain(const _Float16* __restrict__ zs,
                                             float* __restrict__ rowsum,
                                             float* __restrict__ slabel) {
  int rb    = blockIdx.x >> 5;
  int chunk = blockIdx.x & 31;
  int wave  = threadIdx.x >> 6;
  int lane  = threadIdx.x & 63;
  int q = lane >> 4;        // 0..3
  int c = lane & 15;        // 0..15
  int d = c - (q << 2);     // reg r holds diag/label element when d == r
  int rowbase = rb * 128 + wave * 32;
  int colchunk = chunk * 256;

  // A fragments for 2 strips, K=128 (4 k-frags of 32), kept in VGPRs
  f16x8 a[2][4];
#pragma unroll
  for (int s = 0; s < 2; s++) {
    const _Float16* p = zs + (size_t)(rowbase + s * 16 + c) * DD + q * 8;
#pragma unroll
    for (int kk = 0; kk < 4; kk++) a[s][kk] = *(const f16x8*)(p + kk * 32);
  }

  float part[2][4] = {{0.f, 0.f, 0.f, 0.f}, {0.f, 0.f, 0.f, 0.f}};
  const _Float16* bp = zs + (size_t)(colchunk + c) * DD + q * 8;

  auto loadB = [&](f16x8 b[4], int ct) {
    const _Float16* p = bp + (size_t)ct * 16 * DD;
#pragma unroll
    for (int kk = 0; kk < 4; kk++) b[kk] = *(const f16x8*)(p + kk * 32);
  };

  auto compute = [&](const f16x8 b[4], int ct) {
    int colbase = colchunk + ct * 16;
#pragma unroll
    for (int s = 0; s < 2; s++) {
      int sbase = rowbase + s * 16;
      f32x4 acc = {0.f, 0.f, 0.f, 0.f};
#pragma unroll
      for (int kk = 0; kk < 4; kk++)
        acc = __builtin_amdgcn_mfma_f32_16x16x32_f16(a[s][kk], b[kk], acc, 0, 0, 0);
      // C/D layout: col = lane&15, row = (lane>>4)*4 + reg
      if (colbase == (sbase ^ NB)) {          // label tile (wave-uniform branch)
#pragma unroll
        for (int r = 0; r < 4; r++)
          if (d == r) slabel[sbase + c] = acc[r];   // store acc; *ln2 at finalize
      }
      if (colbase == sbase) {                 // diagonal tile: mask self-sim
#pragma unroll
        for (int r = 0; r < 4; r++)
          part[s][r] += (d == r) ? 0.f : EXP2F(acc[r]);
      } else {
#pragma unroll
        for (int r = 0; r < 4; r++)
          part[s][r] += EXP2F(acc[r]);
      }
    }
  };

  f16x8 b0[4], b1[4];
  loadB(b0, 0);
  for (int ct = 0; ct < 16; ct += 2) {         // ping-pong: no reg copies
    loadB(b1, (ct + 1) & 15);
    compute(b0, ct);
    loadB(b0, (ct + 2) & 15);
    compute(b1, ct + 1);
  }

  // reduce exp-partials across the 16 lanes (same row, different cols)
#pragma unroll
  for (int s = 0; s < 2; s++)
#pragma unroll
    for (int r = 0; r < 4; r++) {
      float v = part[s][r];
      v += __shfl_xor(v, 1, 64);
      v += __shfl_xor(v, 2, 64);
      v += __shfl_xor(v, 4, 64);
      v += __shfl_xor(v, 8, 64);
      if (c == 0) atomicAdd(&rowsum[rowbase + s * 16 + (q << 2) + r], v);
    }
}

// ---------------- kernel 3: finalize scalar loss (32 blocks + atomic) --------
__global__ void kfinal(const float* __restrict__ rowsum,
                       const float* __restrict__ slabel,
                       float* __restrict__ out) {
  int i = blockIdx.x * 256 + threadIdx.x;      // 32 blocks * 256 = 8192 rows
  // loss_row = ln2 * (log2(rowsum) - acc_label)
  float acc = LN2 * (LOG2F(rowsum[i]) - slabel[i]);
#pragma unroll
  for (int m = 1; m < 64; m <<= 1) acc += __shfl_xor(acc, m, 64);
  __shared__ float ws[4];
  int tid = threadIdx.x;
  if ((tid & 63) == 0) ws[tid >> 6] = acc;
  __syncthreads();
  if (tid == 0)
    atomicAdd(out, (ws[0] + ws[1] + ws[2] + ws[3]) * (1.0f / (float)NTOT));
}

extern "C" void kernel_launch(void* const* d_in, const int* in_sizes, int n_in,
                              void* d_out, int out_size, void* d_ws, size_t ws_size,
                              hipStream_t stream) {
  const float* zi = (const float*)d_in[0];
  const float* zj = (const float*)d_in[1];
  float* out = (float*)d_out;

  char* ws = (char*)d_ws;
  const size_t ZS_BYTES = (size_t)NTOT * DD * sizeof(_Float16);  // 2 MiB
  _Float16* zs   = (_Float16*)ws;
  float* rowsum  = (float*)(ws + ZS_BYTES);
  float* slabel  = (float*)(ws + ZS_BYTES + NTOT * sizeof(float));

  knorm<<<NTOT / 4, 256, 0, stream>>>(zi, zj, zs, rowsum, out);
  kmain<<<(NTOT / 128) * 32, 256, 0, stream>>>(zs, rowsum, slabel);
  kfinal<<<NTOT / 256, 256, 0, stream>>>(rowsum, slabel, out);
}